// Round 8
// baseline (249.491 us; speedup 1.0000x reference)
//
#include <hip/hip_runtime.h>
#include <math.h>

#define NTH 256
#define NTH2 512
#define LSEQ 2048
#define NF 4096
#define NH 512
#define NS 64
#define NB 8
#define NPAIR 256
#define ASTR 1040
#define TWO_PI 6.2831853071795864769f
// XOR swizzle: bijective, modifies only bits 0-3; spreads every FFT pass's
// lane pattern evenly over banks.
#define SW(i) ((i) ^ (((i) >> 4) & 15) ^ (((i) >> 8) & 15))
#define DR11(l) ((((l) & 15) << 7) | ((((l) >> 4) & 15) << 3) | ((l) >> 8))

#define C16_1 0.9238795325112867f
#define C16_2 0.7071067811865476f
#define C16_3 0.3826834323650898f

__device__ __forceinline__ float frcp(float x) {
    return __builtin_amdgcn_rcpf(x);
}

__device__ __forceinline__ float2 cmul(float2 a, float2 b) {
    return make_float2(a.x*b.x - a.y*b.y, a.x*b.y + a.y*b.x);
}
__device__ __forceinline__ float2 cmulw(float2 a, float wr, float wi) {
    return make_float2(a.x*wr - a.y*wi, a.x*wi + a.y*wr);
}

// ---- stages 2..4 of the 16-point DIF DFT (shared tail) ----
template<bool INV>
__device__ __forceinline__ void fft16_tail(float2* y) {
    const float sg = INV ? -1.f : 1.f;
    const float WR[8] = {1.f, C16_1, C16_2, C16_3, 0.f, -C16_3, -C16_2, -C16_1};
    const float WI[8] = {0.f, -C16_3, -C16_2, -C16_1, -1.f, -C16_1, -C16_2, -C16_3};
    #pragma unroll
    for (int h = 0; h < 16; h += 8)
        #pragma unroll
        for (int j = 0; j < 4; ++j) {
            float2 a = y[h+j], b = y[h+j+4];
            float2 d = make_float2(a.x-b.x, a.y-b.y);
            y[h+j] = make_float2(a.x+b.x, a.y+b.y);
            y[h+j+4] = cmulw(d, WR[2*j], sg*WI[2*j]);
        }
    #pragma unroll
    for (int h = 0; h < 16; h += 4)
        #pragma unroll
        for (int j = 0; j < 2; ++j) {
            float2 a = y[h+j], b = y[h+j+2];
            float2 d = make_float2(a.x-b.x, a.y-b.y);
            y[h+j] = make_float2(a.x+b.x, a.y+b.y);
            y[h+j+2] = (j == 0) ? d : make_float2(sg*d.y, -sg*d.x);
        }
    #pragma unroll
    for (int h = 0; h < 16; h += 2) {
        float2 a = y[h], b = y[h+1];
        y[h] = make_float2(a.x+b.x, a.y+b.y);
        y[h+1] = make_float2(a.x-b.x, a.y-b.y);
    }
}

// ---- full 16-point DIF DFT. Output: Y[k] = y[rev4[k]]. ----
template<bool INV>
__device__ __forceinline__ void fft16(float2* y) {
    const float sg = INV ? -1.f : 1.f;
    const float WR[8] = {1.f, C16_1, C16_2, C16_3, 0.f, -C16_3, -C16_2, -C16_1};
    const float WI[8] = {0.f, -C16_3, -C16_2, -C16_1, -1.f, -C16_1, -C16_2, -C16_3};
    #pragma unroll
    for (int j = 0; j < 8; ++j) {
        float2 a = y[j], b = y[j+8];
        float2 d = make_float2(a.x-b.x, a.y-b.y);
        y[j] = make_float2(a.x+b.x, a.y+b.y);
        y[j+8] = cmulw(d, WR[j], sg*WI[j]);
    }
    fft16_tail<INV>(y);
}

// ---- 8-point DIF DFT. Output: Y[k] = y[rev3[k]]. ----
template<bool INV>
__device__ __forceinline__ void fft8(float2* y) {
    const float sg = INV ? -1.f : 1.f;
    const float WR[4] = {1.f, C16_2, 0.f, -C16_2};
    const float WI[4] = {0.f, -C16_2, -1.f, -C16_2};
    #pragma unroll
    for (int j = 0; j < 4; ++j) {
        float2 a = y[j], b = y[j+4];
        float2 d = make_float2(a.x-b.x, a.y-b.y);
        y[j] = make_float2(a.x+b.x, a.y+b.y);
        y[j+4] = cmulw(d, WR[j], sg*WI[j]);
    }
    #pragma unroll
    for (int h = 0; h < 8; h += 4)
        #pragma unroll
        for (int j = 0; j < 2; ++j) {
            float2 a = y[h+j], b = y[h+j+2];
            float2 d = make_float2(a.x-b.x, a.y-b.y);
            y[h+j] = make_float2(a.x+b.x, a.y+b.y);
            y[h+j+2] = (j == 0) ? d : make_float2(sg*d.y, -sg*d.x);
        }
    #pragma unroll
    for (int h = 0; h < 8; h += 2) {
        float2 a = y[h], b = y[h+1];
        y[h] = make_float2(a.x+b.x, a.y+b.y);
        y[h+1] = make_float2(a.x-b.x, a.y-b.y);
    }
}

// Radix-16 pass on swizzled LDS. INV=false: DIF forward (natural->DR).
// INV=true: DIT inverse (DR->natural). NOTW=true: all twiddles are 1.
template<bool INV, bool NOTW = false>
__device__ __forceinline__ void pass16(float2* s, int base, int str, float ang1) {
    const int rev4[16] = {0,8,4,12,2,10,6,14,1,9,5,13,3,11,7,15};
    float2 y[16];
    if (!INV) {
        #pragma unroll
        for (int j = 0; j < 16; ++j) y[j] = s[SW(base + j*str)];
        fft16<false>(y);
        if (NOTW) {
            #pragma unroll
            for (int k = 0; k < 16; ++k) s[SW(base + k*str)] = y[rev4[k]];
        } else {
            float sn, cs;
            __sincosf(ang1, &sn, &cs);
            float2 wb = make_float2(cs, sn);
            float2 w = make_float2(1.f, 0.f);
            s[SW(base)] = y[0];
            #pragma unroll
            for (int k = 1; k < 16; ++k) {
                w = cmul(w, wb);
                s[SW(base + k*str)] = cmul(y[rev4[k]], w);
            }
        }
    } else {
        if (NOTW) {
            #pragma unroll
            for (int k = 0; k < 16; ++k) y[k] = s[SW(base + k*str)];
        } else {
            float sn, cs;
            __sincosf(ang1, &sn, &cs);
            float2 wb = make_float2(cs, sn);
            float2 w = make_float2(1.f, 0.f);
            y[0] = s[SW(base)];
            #pragma unroll
            for (int k = 1; k < 16; ++k) {
                w = cmul(w, wb);
                y[k] = cmul(s[SW(base + k*str)], w);
            }
        }
        fft16<true>(y);
        #pragma unroll
        for (int j = 0; j < 16; ++j) s[SW(base + j*str)] = y[rev4[j]];
    }
}

// Forward radix-16 pass with implicit-zero top half (j>=8 inputs are zero).
__device__ __forceinline__ void pass16_z(float2* s, int base, int str, float ang1) {
    const int rev4[16] = {0,8,4,12,2,10,6,14,1,9,5,13,3,11,7,15};
    const float WR[8] = {1.f, C16_1, C16_2, C16_3, 0.f, -C16_3, -C16_2, -C16_1};
    const float WI[8] = {0.f, -C16_3, -C16_2, -C16_1, -1.f, -C16_1, -C16_2, -C16_3};
    float2 y[16];
    float sn, cs;
    __sincosf(ang1, &sn, &cs);
    float2 wb = make_float2(cs, sn);
    #pragma unroll
    for (int j = 0; j < 8; ++j) y[j] = s[SW(base + j*str)];
    #pragma unroll
    for (int j = 0; j < 8; ++j) y[j+8] = cmulw(y[j], WR[j], WI[j]);
    fft16_tail<false>(y);
    float2 w = make_float2(1.f, 0.f);
    s[SW(base)] = y[0];
    #pragma unroll
    for (int k = 1; k < 16; ++k) {
        w = cmul(w, wb);
        s[SW(base + k*str)] = cmul(y[rev4[k]], w);
    }
}

// Final inverse radix-16 pass: only j<8 outputs (t<2048) are needed.
__device__ __forceinline__ void pass16_li(float2* s, int base, int str, float ang1) {
    const int rev4[16] = {0,8,4,12,2,10,6,14,1,9,5,13,3,11,7,15};
    float2 y[16];
    float sn, cs;
    __sincosf(ang1, &sn, &cs);
    float2 wb = make_float2(cs, sn);
    float2 w = make_float2(1.f, 0.f);
    y[0] = s[SW(base)];
    #pragma unroll
    for (int k = 1; k < 16; ++k) {
        w = cmul(w, wb);
        y[k] = cmul(s[SW(base + k*str)], w);
    }
    fft16<true>(y);
    #pragma unroll
    for (int j = 0; j < 8; ++j) s[SW(base + j*str)] = y[rev4[j]];
}

template<bool INV, bool NOTW = false>
__device__ __forceinline__ void pass8(float2* s, int base, int str, float ang1) {
    const int rev3[8] = {0,4,2,6,1,5,3,7};
    float2 y[8];
    if (!INV) {
        #pragma unroll
        for (int j = 0; j < 8; ++j) y[j] = s[SW(base + j*str)];
        fft8<false>(y);
        if (NOTW) {
            #pragma unroll
            for (int k = 0; k < 8; ++k) s[SW(base + k*str)] = y[rev3[k]];
        } else {
            float sn, cs;
            __sincosf(ang1, &sn, &cs);
            float2 wb = make_float2(cs, sn);
            float2 w = make_float2(1.f, 0.f);
            s[SW(base)] = y[0];
            #pragma unroll
            for (int k = 1; k < 8; ++k) {
                w = cmul(w, wb);
                s[SW(base + k*str)] = cmul(y[rev3[k]], w);
            }
        }
    } else {
        if (NOTW) {
            #pragma unroll
            for (int k = 0; k < 8; ++k) y[k] = s[SW(base + k*str)];
        } else {
            float sn, cs;
            __sincosf(ang1, &sn, &cs);
            float2 wb = make_float2(cs, sn);
            float2 w = make_float2(1.f, 0.f);
            y[0] = s[SW(base)];
            #pragma unroll
            for (int k = 1; k < 8; ++k) {
                w = cmul(w, wb);
                y[k] = cmul(s[SW(base + k*str)], w);
            }
        }
        fft8<true>(y);
        #pragma unroll
        for (int j = 0; j < 8; ++j) s[SW(base + j*str)] = y[rev3[j]];
    }
}

// FUSED k_tu + k_cauchy: 2048 blocks. Workgroups go to XCD (bid % 8), so
// the type selector uses bit 3: blocks 0-7 -> transpose (XCDs 0-7), blocks
// 8-15 -> Cauchy (XCDs 0-7), alternating stripes of 8. Both populations
// are co-resident on EVERY XCD/CU: the transpose's HBM streams overlap
// the Cauchy's VALU chains. (Round 7 used bid&1, which put all transposes
// on even XCDs and all Cauchy on odd XCDs -- no overlap, 2x Cauchy time.)
// One overlaid 33,280-B shared buffer serves both paths (union layout).
__global__ __launch_bounds__(NTH, 4) void k_tc(
    const float2* __restrict__ u2, float2* __restrict__ W,
    const float* __restrict__ Lre, const float* __restrict__ Lim,
    const float* __restrict__ Pm, const float* __restrict__ Bm,
    const float* __restrict__ Cm, const float* __restrict__ logstep,
    float2* __restrict__ Ag)
{
    __shared__ float4 smem4[2080];     // 33,280 B: max(tile 64x65 f2, cauchy tabs)
    const int bid = blockIdx.x;
    const int id = ((bid >> 4) << 3) | (bid & 7);   // rank within population
    const int tid = threadIdx.x;
    if (((bid >> 3) & 1) == 0) {
        // ---------------- transpose u [b][t][hp] -> W [hp][b][t] ----------------
        float2 (*tile)[65] = reinterpret_cast<float2(*)[65]>(smem4);
        const int t0 = (id & 31) * 64;
        const int hp0 = ((id >> 5) & 3) * 64;
        const int b = id >> 7;
        const int tx = tid & 63, ty = tid >> 6;
        #pragma unroll
        for (int r = 0; r < 64; r += 4)
            tile[r + ty][tx] = u2[((size_t)b * LSEQ + t0 + r + ty) * NPAIR + hp0 + tx];
        __syncthreads();
        #pragma unroll
        for (int r = 0; r < 64; r += 4)
            W[(((size_t)(hp0 + r + ty) * NB + b) << 11) + t0 + tx] = tile[tx][r + ty];
    } else {
        // ---------------- Cauchy: 2 blocks/head, 4 freqs/thread ----------------
        float4* cA = (float4*)smem4;              // [64] dre, dre^2, lam_im, |P|^2
        float4* cB = cA + NS;                     // [64] conj(C)B, conj(C)P
        float2* cC = (float2*)(cB + NS);          // [64] conj(P)B
        float4* shx4 = (float4*)(cC + NS);        // [256]
        float4* shy4 = shx4 + NTH;                // [256]
        const int h = id >> 1;
        const int q = id & 1;
        if (tid < NS) {
            int i = h * NS + tid;
            float Lx = fminf(Lre[i], -1e-4f), Ly = Lim[i];
            float Px = Pm[2*i], Py = Pm[2*i+1];
            float Bx = Bm[2*i], By = Bm[2*i+1];
            float Cx = Cm[2*i], Cy = Cm[2*i+1];
            float dre = -Lx;
            cA[tid] = make_float4(dre, dre*dre, Ly, Px*Px + Py*Py);
            cB[tid] = make_float4(Cx*Bx + Cy*By, Cx*By - Cy*Bx,
                                  Cx*Px + Cy*Py, Cx*Py - Cy*Px);
            cC[tid] = make_float2(Px*Bx + Py*By, Px*By - Py*Bx);
        }
        __syncthreads();
        const float step = expf(logstep[h]);
        const float a2s = 2.0f / step;
        float tg[4], g1v[4];
        #pragma unroll
        for (int j = 0; j < 4; ++j) {
            int l = (tid < 128) ? (q * 512 + 4 * tid + j)
                                : (LSEQ - (q * 512 + 4 * (tid - 128) + j));
            float r = (float)l * (1.0f / (float)LSEQ);
            tg[j] = sinpif(r) * frcp(cospif(r));     // tan(pi*l/L)
            g1v[j] = a2s * tg[j];
        }
        float a0[4] = {0,0,0,0}, a1[4] = {0,0,0,0};
        float a2[4] = {0,0,0,0}, a3[4] = {0,0,0,0};
        float a4[4] = {0,0,0,0}, a5[4] = {0,0,0,0};
        float a6[4] = {0,0,0,0}, a7[4] = {0,0,0,0};
        for (int n = 0; n < NS; ++n) {
            float4 ca = cA[n];
            float4 cb = cB[n];
            float2 cc = cC[n];
            #pragma unroll
            for (int j = 0; j < 4; ++j) {
                float di = g1v[j] - ca.z;
                float iv = frcp(fmaf(di, di, ca.y));
                float rx = ca.x * iv, ry = di * iv;  // rec = rx - i*ry
                a0[j] += cb.x*rx + cb.y*ry;  a1[j] += cb.y*rx - cb.x*ry;
                a2[j] += cb.z*rx + cb.w*ry;  a3[j] += cb.w*rx - cb.z*ry;
                a4[j] += cc.x*rx + cc.y*ry;  a5[j] += cc.y*rx - cc.x*ry;
                a6[j] += ca.w*rx;            a7[j] -= ca.w*ry;
            }
        }
        // finalize: (1 + i*tg) * (s00 - s01*s10/(1+s11))
        float arx[4], ary[4];
        #pragma unroll
        for (int j = 0; j < 4; ++j) {
            float denx = 1.0f + a6[j], deny = a7[j];
            float dinv = frcp(denx*denx + deny*deny);
            float numx = a2[j]*a4[j] - a3[j]*a5[j];
            float numy = a2[j]*a5[j] + a3[j]*a4[j];
            float qx = (numx*denx + numy*deny) * dinv;
            float qy = (numy*denx - numx*deny) * dinv;
            float kx = a0[j] - qx, ky = a1[j] - qy;
            arx[j] = kx - tg[j]*ky;
            ary[j] = ky + tg[j]*kx;
        }
        shx4[tid] = make_float4(arx[0], arx[1], arx[2], arx[3]);
        shy4[tid] = make_float4(ary[0], ary[1], ary[2], ary[3]);
        __syncthreads();
        if (tid < 128) {
            // A[l] = (at[l] + conj(at[2048-l]))/2 ; mirror sits at tid+128
            float4 mx = shx4[tid + 128], my = shy4[tid + 128];
            float2 A0 = make_float2(0.5f*(arx[0] + mx.x), 0.5f*(ary[0] - my.x));
            float2 A1 = make_float2(0.5f*(arx[1] + mx.y), 0.5f*(ary[1] - my.y));
            float2 A2 = make_float2(0.5f*(arx[2] + mx.z), 0.5f*(ary[2] - my.z));
            float2 A3 = make_float2(0.5f*(arx[3] + mx.w), 0.5f*(ary[3] - my.w));
            float4* dst = (float4*)(Ag + (size_t)h * ASTR + (q * 512 + 4 * tid));
            dst[0] = make_float4(A0.x, A0.y, A1.x, A1.y);
            dst[1] = make_float4(A2.x, A2.y, A3.x, A3.y);
        }
        if (q == 0 && tid == 0) {
            // l = 1024: tan -> inf limit, A[1024] = Re((step/2)*sum(conj(C)B))
            float sx = 0.f;
            for (int n = 0; n < NS; ++n) sx += cB[n].x;
            Ag[(size_t)h * ASTR + 1024] = make_float2(0.5f * step * sx, 0.f);
        }
    }
}

// Transpose W [hp][b][t]f2 -> out [b][t][hp]f2.
__global__ __launch_bounds__(NTH) void k_ty(
    const float2* __restrict__ W, float2* __restrict__ out2)
{
    __shared__ float2 tile[64][65];
    const int t0 = blockIdx.x * 64, hp0 = blockIdx.y * 64, b = blockIdx.z;
    const int tx = threadIdx.x & 63, ty = threadIdx.x >> 6;
    #pragma unroll
    for (int r = 0; r < 64; r += 4)   // tile[hp_local][t_local]
        tile[r + ty][tx] = W[(((size_t)(hp0 + r + ty) * NB + b) << 11) + t0 + tx];
    __syncthreads();
    #pragma unroll
    for (int r = 0; r < 64; r += 4)
        out2[((size_t)b * LSEQ + t0 + r + ty) * NPAIR + hp0 + tx] = tile[tx][r + ty];
}

// Kf spectrum per head (512 blocks, ~24 KB LDS).
// Even bins: directly from A (stashed in padded LDS), coalesced writes.
// Odd bins: IDIT-2048(A) -> K -> modulate e^{-2pi i t/4096} -> DIF-2048.
__global__ __launch_bounds__(NTH) void k_kspec(
    const float2* __restrict__ Ag, const float* __restrict__ Dp,
    float2* __restrict__ KfP)
{
    __shared__ float2 sW[LSEQ];
    __shared__ float2 sA[1040];   // A[0..1024] at sA[l + (l>>7)] (pad: 2-way banks)
    const int h = blockIdx.x;
    const int tid = threadIdx.x;
    const float2* Ah = Ag + (size_t)h * ASTR;
    for (int l = tid; l <= LSEQ/2; l += NTH) {
        float2 A = Ah[l];
        sA[l + (l >> 7)] = A;
        sW[SW(DR11(l))] = A;
        if (l > 0 && l < LSEQ/2)
            sW[SW(DR11(LSEQ - l))] = make_float2(A.x, -A.y);
    }
    __syncthreads();
    // inverse DIT-2048 (DR -> natural time)
    pass8<true, true>(sW, tid << 3, 1, 0.f);
    __syncthreads();
    if (tid < 128) pass16<true>(sW, ((tid >> 3) << 7) | (tid & 7), 8,
                                TWO_PI * (float)(tid & 7) / 128.f);
    __syncthreads();
    if (tid < 128) pass16<true>(sW, tid, 128, TWO_PI * (float)tid / 2048.f);
    __syncthreads();
    // modulate: K[t]/2048 * e^{-2pi i t/4096}
    for (int t = tid; t < LSEQ; t += NTH) {
        float kv = sW[SW(t)].x * (1.0f / (float)LSEQ);
        float sn, cs;
        __sincosf(-TWO_PI * (float)t / (float)NF, &sn, &cs);
        sW[SW(t)] = make_float2(kv * cs, kv * sn);
    }
    __syncthreads();
    // forward DIF-2048 (natural -> DR spectrum)
    if (tid < 128) pass16<false>(sW, tid, 128, -TWO_PI * (float)tid / 2048.f);
    __syncthreads();
    if (tid < 128) pass16<false>(sW, ((tid >> 3) << 7) | (tid & 7), 8,
                                 -TWO_PI * (float)(tid & 7) / 128.f);
    __syncthreads();
    pass8<false, true>(sW, tid << 3, 1, 0.f);
    __syncthreads();
    const float dD = Dp[h];
    const float s4 = 1.0f / (float)NF;
    float2* Kh = KfP + (size_t)h * NF;
    #pragma unroll
    for (int g = 0; g < 8; ++g) {      // positions with (p>>8) odd <=> k odd
        int p = (2*g + 1) * 256 + tid;
        int k = ((p & 15) << 8) | (p & 240) | (p >> 8);
        int m = k >> 1;
        float2 v = sW[SW(DR11(m))];
        Kh[p] = make_float2((v.x + dD) * s4, v.y * s4);
    }
    #pragma unroll
    for (int g = 0; g < 8; ++g) {      // positions with (p>>8) even <=> k even
        int p = g * 512 + tid;         // k = ((tid&15)<<8)|(tid&240)|2g
        int m = (((tid & 15) << 7) | ((tid & 240) >> 1)) | g;   // = k>>1
        float2 v; float sgn;
        if (m <= 1024) { v = sA[m + (m >> 7)]; sgn = 1.f; }
        else { int mm = LSEQ - m; v = sA[mm + (mm >> 7)]; sgn = -1.f; }
        Kh[p] = make_float2((v.x + dD) * s4, sgn * v.y * s4);
    }
}

// FFT convolution: TWO sequences (same hp, b = 2*bb and 2*bb+1) per
// 512-thread block. Each 4-wave half owns one 4096-pt spectrum in its own
// 32-KB LDS region; barriers are shared. Kf row-pair (64 KB) is read once
// per block; the 4 same-hp blocks sit on one XCD (idx%8 = hp&7) so Kf is
// fetched ~once per XCD. This is the round-3 proven 60-us structure:
// every phase self-contained (no registers live across barriers).
__global__ __launch_bounds__(NTH2, 4) void k_conv(
    float2* __restrict__ W, const float2* __restrict__ Kf)
{
    __shared__ float2 s[2 * NF];
    const int idx = blockIdx.x;
    const int hp = ((idx >> 5) << 3) | (idx & 7);
    const int bb = (idx >> 3) & 3;
    const int half = threadIdx.x >> 8;
    const int t = threadIdx.x & 255;
    const int b = bb * 2 + half;
    float2* sh = s + (half << 12);
    float4* w4 = (float4*)(W + (((size_t)hp * NB + b) << 11));
    for (int i = t; i < 1024; i += 256) {
        float4 v = w4[i];
        sh[SW(2*i)]   = make_float2(v.x, v.y);
        sh[SW(2*i+1)] = make_float2(v.z, v.w);
    }
    __syncthreads();
    // forward DIF 4096 = 16*16*16 (pass 1 exploits zero top half)
    pass16_z(sh, t, 256, -TWO_PI * (float)t / 4096.f);
    __syncthreads();
    pass16<false>(sh, ((t >> 4) << 8) | (t & 15), 16,
                  -TWO_PI * (float)(t & 15) / 256.f);
    __syncthreads();
    pass16<false, true>(sh, t << 4, 1, 0.f);
    __syncthreads();
    // pointwise in permuted domain (pair-ownership: p <= pp, write both)
    const float2* K0 = Kf + (size_t)(2 * hp) * NF;
    const float2* K1 = K0 + NF;
    for (int p = t; p < NF; p += 256) {
        int k  = ((p & 15) << 8) | (p & 240) | (p >> 8);       // bin at pos p
        int kc = (NF - k) & (NF - 1);
        int pp = ((kc & 15) << 8) | (kc & 240) | (kc >> 8);    // conj bin pos
        if (p > pp) continue;
        if (p == pp) {   // self-conjugate bins (k = 0, 2048)
            float2 X = sh[SW(p)];
            float2 g0 = K0[p], g1 = K1[p];
            sh[SW(p)] = make_float2(X.x*g0.x - X.y*g1.y, X.x*g0.y + X.y*g1.x);
        } else {
            float2 Xa = sh[SW(p)], Xb = sh[SW(pp)];
            float2 U0 = make_float2(0.5f*(Xa.x + Xb.x), 0.5f*(Xa.y - Xb.y));
            float2 df = make_float2(Xa.x - Xb.x, Xa.y + Xb.y);
            float2 U1 = make_float2(0.5f*df.y, -0.5f*df.x);
            float2 A0 = K0[p], A1 = K1[p], B0 = K0[pp], B1 = K1[pp];
            float2 y0 = cmul(U0, A0), y1 = cmul(U1, A1);
            sh[SW(p)] = make_float2(y0.x - y1.y, y0.y + y1.x);
            float2 U0c = make_float2(U0.x, -U0.y);
            float2 U1c = make_float2(U1.x, -U1.y);
            float2 z0 = cmul(U0c, B0), z1 = cmul(U1c, B1);
            sh[SW(pp)] = make_float2(z0.x - z1.y, z0.y + z1.x);
        }
    }
    __syncthreads();
    // inverse DIT 4096 (last pass writes only t<2048)
    pass16<true, true>(sh, t << 4, 1, 0.f);
    __syncthreads();
    pass16<true>(sh, ((t >> 4) << 8) | (t & 15), 16,
                 TWO_PI * (float)(t & 15) / 256.f);
    __syncthreads();
    pass16_li(sh, t, 256, TWO_PI * (float)t / 4096.f);
    __syncthreads();
    for (int i = t; i < 1024; i += 256) {
        float2 a = sh[SW(2*i)], c = sh[SW(2*i+1)];
        w4[i] = make_float4(a.x, a.y, c.x, c.y);
    }
}

extern "C" void kernel_launch(void* const* d_in, const int* in_sizes, int n_in,
                              void* d_out, int out_size, void* d_ws, size_t ws_size,
                              hipStream_t stream) {
    const float* u   = (const float*)d_in[0];
    const float* Lre = (const float*)d_in[1];
    const float* Lim = (const float*)d_in[2];
    const float* P   = (const float*)d_in[3];
    const float* B   = (const float*)d_in[4];
    const float* C   = (const float*)d_in[5];
    const float* D   = (const float*)d_in[6];
    const float* ls  = (const float*)d_in[7];

    float2* KfP = (float2*)d_ws;                                   // 16.8 MB
    float2* W   = (float2*)((char*)d_ws +
                            (size_t)NH * NF * sizeof(float2));     // 33.6 MB
    float2* Ag  = (float2*)d_out;     // 4.3 MB scratch, overwritten by k_ty

    k_tc    <<<2048, NTH, 0, stream>>>((const float2*)u, W,
                                       Lre, Lim, P, B, C, ls, Ag);
    k_kspec <<<NH, NTH, 0, stream>>>(Ag, D, KfP);
    k_conv  <<<NPAIR * NB / 2, NTH2, 0, stream>>>(W, KfP);
    k_ty    <<<dim3(32, 4, 8), NTH, 0, stream>>>(W, (float2*)d_out);
}

// Round 9
// 217.068 us; speedup vs baseline: 1.1494x; 1.1494x over previous
//
#include <hip/hip_runtime.h>
#include <math.h>

#define NTH 256
#define NTH2 512
#define LSEQ 2048
#define NF 4096
#define NH 512
#define NS 64
#define NB 8
#define NPAIR 256
#define TWO_PI 6.2831853071795864769f
// XOR swizzle: bijective, modifies only bits 0-3; spreads every FFT pass's
// lane pattern evenly over banks.
#define SW(i) ((i) ^ (((i) >> 4) & 15) ^ (((i) >> 8) & 15))
#define DR11(l) ((((l) & 15) << 7) | ((((l) >> 4) & 15) << 3) | ((l) >> 8))

#define C16_1 0.9238795325112867f
#define C16_2 0.7071067811865476f
#define C16_3 0.3826834323650898f

__device__ __forceinline__ float frcp(float x) {
    return __builtin_amdgcn_rcpf(x);
}

__device__ __forceinline__ float2 cmul(float2 a, float2 b) {
    return make_float2(a.x*b.x - a.y*b.y, a.x*b.y + a.y*b.x);
}
__device__ __forceinline__ float2 cmulw(float2 a, float wr, float wi) {
    return make_float2(a.x*wr - a.y*wi, a.x*wi + a.y*wr);
}

// ---- stages 2..4 of the 16-point DIF DFT (shared tail) ----
template<bool INV>
__device__ __forceinline__ void fft16_tail(float2* y) {
    const float sg = INV ? -1.f : 1.f;
    const float WR[8] = {1.f, C16_1, C16_2, C16_3, 0.f, -C16_3, -C16_2, -C16_1};
    const float WI[8] = {0.f, -C16_3, -C16_2, -C16_1, -1.f, -C16_1, -C16_2, -C16_3};
    #pragma unroll
    for (int h = 0; h < 16; h += 8)
        #pragma unroll
        for (int j = 0; j < 4; ++j) {
            float2 a = y[h+j], b = y[h+j+4];
            float2 d = make_float2(a.x-b.x, a.y-b.y);
            y[h+j] = make_float2(a.x+b.x, a.y+b.y);
            y[h+j+4] = cmulw(d, WR[2*j], sg*WI[2*j]);
        }
    #pragma unroll
    for (int h = 0; h < 16; h += 4)
        #pragma unroll
        for (int j = 0; j < 2; ++j) {
            float2 a = y[h+j], b = y[h+j+2];
            float2 d = make_float2(a.x-b.x, a.y-b.y);
            y[h+j] = make_float2(a.x+b.x, a.y+b.y);
            y[h+j+2] = (j == 0) ? d : make_float2(sg*d.y, -sg*d.x);
        }
    #pragma unroll
    for (int h = 0; h < 16; h += 2) {
        float2 a = y[h], b = y[h+1];
        y[h] = make_float2(a.x+b.x, a.y+b.y);
        y[h+1] = make_float2(a.x-b.x, a.y-b.y);
    }
}

// ---- full 16-point DIF DFT. Output: Y[k] = y[rev4[k]]. ----
template<bool INV>
__device__ __forceinline__ void fft16(float2* y) {
    const float sg = INV ? -1.f : 1.f;
    const float WR[8] = {1.f, C16_1, C16_2, C16_3, 0.f, -C16_3, -C16_2, -C16_1};
    const float WI[8] = {0.f, -C16_3, -C16_2, -C16_1, -1.f, -C16_1, -C16_2, -C16_3};
    #pragma unroll
    for (int j = 0; j < 8; ++j) {
        float2 a = y[j], b = y[j+8];
        float2 d = make_float2(a.x-b.x, a.y-b.y);
        y[j] = make_float2(a.x+b.x, a.y+b.y);
        y[j+8] = cmulw(d, WR[j], sg*WI[j]);
    }
    fft16_tail<INV>(y);
}

// ---- 8-point DIF DFT. Output: Y[k] = y[rev3[k]]. ----
template<bool INV>
__device__ __forceinline__ void fft8(float2* y) {
    const float sg = INV ? -1.f : 1.f;
    const float WR[4] = {1.f, C16_2, 0.f, -C16_2};
    const float WI[4] = {0.f, -C16_2, -1.f, -C16_2};
    #pragma unroll
    for (int j = 0; j < 4; ++j) {
        float2 a = y[j], b = y[j+4];
        float2 d = make_float2(a.x-b.x, a.y-b.y);
        y[j] = make_float2(a.x+b.x, a.y+b.y);
        y[j+4] = cmulw(d, WR[j], sg*WI[j]);
    }
    #pragma unroll
    for (int h = 0; h < 8; h += 4)
        #pragma unroll
        for (int j = 0; j < 2; ++j) {
            float2 a = y[h+j], b = y[h+j+2];
            float2 d = make_float2(a.x-b.x, a.y-b.y);
            y[h+j] = make_float2(a.x+b.x, a.y+b.y);
            y[h+j+2] = (j == 0) ? d : make_float2(sg*d.y, -sg*d.x);
        }
    #pragma unroll
    for (int h = 0; h < 8; h += 2) {
        float2 a = y[h], b = y[h+1];
        y[h] = make_float2(a.x+b.x, a.y+b.y);
        y[h+1] = make_float2(a.x-b.x, a.y-b.y);
    }
}

// Radix-16 pass on swizzled LDS. INV=false: DIF forward (natural->DR).
// INV=true: DIT inverse (DR->natural). NOTW=true: all twiddles are 1.
template<bool INV, bool NOTW = false>
__device__ __forceinline__ void pass16(float2* s, int base, int str, float ang1) {
    const int rev4[16] = {0,8,4,12,2,10,6,14,1,9,5,13,3,11,7,15};
    float2 y[16];
    if (!INV) {
        #pragma unroll
        for (int j = 0; j < 16; ++j) y[j] = s[SW(base + j*str)];
        fft16<false>(y);
        if (NOTW) {
            #pragma unroll
            for (int k = 0; k < 16; ++k) s[SW(base + k*str)] = y[rev4[k]];
        } else {
            float sn, cs;
            __sincosf(ang1, &sn, &cs);
            float2 wb = make_float2(cs, sn);
            float2 w = make_float2(1.f, 0.f);
            s[SW(base)] = y[0];
            #pragma unroll
            for (int k = 1; k < 16; ++k) {
                w = cmul(w, wb);
                s[SW(base + k*str)] = cmul(y[rev4[k]], w);
            }
        }
    } else {
        if (NOTW) {
            #pragma unroll
            for (int k = 0; k < 16; ++k) y[k] = s[SW(base + k*str)];
        } else {
            float sn, cs;
            __sincosf(ang1, &sn, &cs);
            float2 wb = make_float2(cs, sn);
            float2 w = make_float2(1.f, 0.f);
            y[0] = s[SW(base)];
            #pragma unroll
            for (int k = 1; k < 16; ++k) {
                w = cmul(w, wb);
                y[k] = cmul(s[SW(base + k*str)], w);
            }
        }
        fft16<true>(y);
        #pragma unroll
        for (int j = 0; j < 16; ++j) s[SW(base + j*str)] = y[rev4[j]];
    }
}

// Forward radix-16 pass with implicit-zero top half (j>=8 inputs are zero).
__device__ __forceinline__ void pass16_z(float2* s, int base, int str, float ang1) {
    const int rev4[16] = {0,8,4,12,2,10,6,14,1,9,5,13,3,11,7,15};
    const float WR[8] = {1.f, C16_1, C16_2, C16_3, 0.f, -C16_3, -C16_2, -C16_1};
    const float WI[8] = {0.f, -C16_3, -C16_2, -C16_1, -1.f, -C16_1, -C16_2, -C16_3};
    float2 y[16];
    float sn, cs;
    __sincosf(ang1, &sn, &cs);
    float2 wb = make_float2(cs, sn);
    #pragma unroll
    for (int j = 0; j < 8; ++j) y[j] = s[SW(base + j*str)];
    #pragma unroll
    for (int j = 0; j < 8; ++j) y[j+8] = cmulw(y[j], WR[j], WI[j]);
    fft16_tail<false>(y);
    float2 w = make_float2(1.f, 0.f);
    s[SW(base)] = y[0];
    #pragma unroll
    for (int k = 1; k < 16; ++k) {
        w = cmul(w, wb);
        s[SW(base + k*str)] = cmul(y[rev4[k]], w);
    }
}

// Final inverse radix-16 pass: only j<8 outputs (t<2048) are needed.
__device__ __forceinline__ void pass16_li(float2* s, int base, int str, float ang1) {
    const int rev4[16] = {0,8,4,12,2,10,6,14,1,9,5,13,3,11,7,15};
    float2 y[16];
    float sn, cs;
    __sincosf(ang1, &sn, &cs);
    float2 wb = make_float2(cs, sn);
    float2 w = make_float2(1.f, 0.f);
    y[0] = s[SW(base)];
    #pragma unroll
    for (int k = 1; k < 16; ++k) {
        w = cmul(w, wb);
        y[k] = cmul(s[SW(base + k*str)], w);
    }
    fft16<true>(y);
    #pragma unroll
    for (int j = 0; j < 8; ++j) s[SW(base + j*str)] = y[rev4[j]];
}

template<bool INV, bool NOTW = false>
__device__ __forceinline__ void pass8(float2* s, int base, int str, float ang1) {
    const int rev3[8] = {0,4,2,6,1,5,3,7};
    float2 y[8];
    if (!INV) {
        #pragma unroll
        for (int j = 0; j < 8; ++j) y[j] = s[SW(base + j*str)];
        fft8<false>(y);
        if (NOTW) {
            #pragma unroll
            for (int k = 0; k < 8; ++k) s[SW(base + k*str)] = y[rev3[k]];
        } else {
            float sn, cs;
            __sincosf(ang1, &sn, &cs);
            float2 wb = make_float2(cs, sn);
            float2 w = make_float2(1.f, 0.f);
            s[SW(base)] = y[0];
            #pragma unroll
            for (int k = 1; k < 8; ++k) {
                w = cmul(w, wb);
                s[SW(base + k*str)] = cmul(y[rev3[k]], w);
            }
        }
    } else {
        if (NOTW) {
            #pragma unroll
            for (int k = 0; k < 8; ++k) y[k] = s[SW(base + k*str)];
        } else {
            float sn, cs;
            __sincosf(ang1, &sn, &cs);
            float2 wb = make_float2(cs, sn);
            float2 w = make_float2(1.f, 0.f);
            y[0] = s[SW(base)];
            #pragma unroll
            for (int k = 1; k < 8; ++k) {
                w = cmul(w, wb);
                y[k] = cmul(s[SW(base + k*str)], w);
            }
        }
        fft8<true>(y);
        #pragma unroll
        for (int j = 0; j < 8; ++j) s[SW(base + j*str)] = y[rev3[j]];
    }
}

// Transpose u [b][t][hp]f2 -> W [hp][b][t]f2 via 64x64 LDS tiles.
__global__ __launch_bounds__(NTH) void k_tu(
    const float2* __restrict__ u2, float2* __restrict__ W)
{
    __shared__ float2 tile[64][65];
    const int t0 = blockIdx.x * 64, hp0 = blockIdx.y * 64, b = blockIdx.z;
    const int tx = threadIdx.x & 63, ty = threadIdx.x >> 6;
    #pragma unroll
    for (int r = 0; r < 64; r += 4)
        tile[r + ty][tx] = u2[((size_t)b * LSEQ + t0 + r + ty) * NPAIR + hp0 + tx];
    __syncthreads();
    #pragma unroll
    for (int r = 0; r < 64; r += 4)
        W[(((size_t)(hp0 + r + ty) * NB + b) << 11) + t0 + tx] = tile[tx][r + ty];
}

// Transpose W [hp][b][t]f2 -> out [b][t][hp]f2.
__global__ __launch_bounds__(NTH) void k_ty(
    const float2* __restrict__ W, float2* __restrict__ out2)
{
    __shared__ float2 tile[64][65];
    const int t0 = blockIdx.x * 64, hp0 = blockIdx.y * 64, b = blockIdx.z;
    const int tx = threadIdx.x & 63, ty = threadIdx.x >> 6;
    #pragma unroll
    for (int r = 0; r < 64; r += 4)   // tile[hp_local][t_local]
        tile[r + ty][tx] = W[(((size_t)(hp0 + r + ty) * NB + b) << 11) + t0 + tx];
    __syncthreads();
    #pragma unroll
    for (int r = 0; r < 64; r += 4)
        out2[((size_t)b * LSEQ + t0 + r + ty) * NPAIR + hp0 + tx] = tile[tx][r + ty];
}

// MERGED k_cauchy + k_kspec: ONE block per head (512 blocks). The Cauchy
// phase computes all 2048 frequencies (8 per thread, by l-index into LDS),
// the mirror-combine produces A in-LDS, and the kspec pipeline (verbatim
// round-3 code) runs in the same block. Removes the Ag global round-trip
// (8.4 MB), one kernel launch, and the grid-wide producer/consumer drain.
// LDS ~43 KB -> 2-3 blocks/CU; launch_bounds(256,2) caps VGPR at 256 so
// the 64 accumulators never spill (no arrays live across barriers).
__global__ __launch_bounds__(NTH, 2) void k_ck(
    const float* __restrict__ Lre, const float* __restrict__ Lim,
    const float* __restrict__ Pm, const float* __restrict__ Bm,
    const float* __restrict__ Cm, const float* __restrict__ logstep,
    const float* __restrict__ Dp, float2* __restrict__ KfP)
{
    __shared__ float2 sW[LSEQ];        // 16 KB
    __shared__ float2 sA[1040];        // 8.3 KB: A[0..1024] at sA[l+(l>>7)]
    __shared__ float Lx[1024], Ly[1024], Ux[1024], Uy[1024];  // 16 KB
    __shared__ float4 cA[NS];          // dre, dre^2, lam_im, |P|^2
    __shared__ float4 cB[NS];          // conj(C)B, conj(C)P
    __shared__ float2 cC[NS];          // conj(P)B
    __shared__ float2 aMid;
    const int h = blockIdx.x;
    const int tid = threadIdx.x;
    if (tid < NS) {
        int i = h * NS + tid;
        float Lxx = fminf(Lre[i], -1e-4f), Lyy = Lim[i];
        float Px = Pm[2*i], Py = Pm[2*i+1];
        float Bx = Bm[2*i], By = Bm[2*i+1];
        float Cx = Cm[2*i], Cy = Cm[2*i+1];
        float dre = -Lxx;
        cA[tid] = make_float4(dre, dre*dre, Lyy, Px*Px + Py*Py);
        cB[tid] = make_float4(Cx*Bx + Cy*By, Cx*By - Cy*Bx,
                              Cx*Px + Cy*Py, Cx*Py - Cy*Px);
        cC[tid] = make_float2(Px*Bx + Py*By, Px*By - Py*Bx);
    }
    __syncthreads();
    const float step = expf(logstep[h]);
    const float a2s = 2.0f / step;
    // ---- Cauchy: 8 frequencies per thread ----
    // tid<128: idx = 8*tid+j, l = idx (0..1023) -> Lx/Ly[idx]
    // tid>=128: idx = 8*(tid-128)+j, l = 2048-idx (2048..1025) -> Ux/Uy[idx]
    const int lo = (tid < 128);
    const int ib = lo ? (8 * tid) : (8 * (tid - 128));
    float tg[8], g1v[8];
    #pragma unroll
    for (int j = 0; j < 8; ++j) {
        int l = lo ? (ib + j) : (LSEQ - (ib + j));
        float r = (float)l * (1.0f / (float)LSEQ);
        tg[j] = sinpif(r) * frcp(cospif(r));     // tan(pi*l/L)
        g1v[j] = a2s * tg[j];
    }
    float a0[8] = {0,0,0,0,0,0,0,0}, a1[8] = {0,0,0,0,0,0,0,0};
    float a2[8] = {0,0,0,0,0,0,0,0}, a3[8] = {0,0,0,0,0,0,0,0};
    float a4[8] = {0,0,0,0,0,0,0,0}, a5[8] = {0,0,0,0,0,0,0,0};
    float a6[8] = {0,0,0,0,0,0,0,0}, a7[8] = {0,0,0,0,0,0,0,0};
    for (int n = 0; n < NS; ++n) {
        float4 ca = cA[n];
        float4 cb = cB[n];
        float2 cc = cC[n];
        #pragma unroll
        for (int j = 0; j < 8; ++j) {
            float di = g1v[j] - ca.z;
            float iv = frcp(fmaf(di, di, ca.y));
            float rx = ca.x * iv, ry = di * iv;  // rec = rx - i*ry
            a0[j] += cb.x*rx + cb.y*ry;  a1[j] += cb.y*rx - cb.x*ry;
            a2[j] += cb.z*rx + cb.w*ry;  a3[j] += cb.w*rx - cb.z*ry;
            a4[j] += cc.x*rx + cc.y*ry;  a5[j] += cc.y*rx - cc.x*ry;
            a6[j] += ca.w*rx;            a7[j] -= ca.w*ry;
        }
    }
    // finalize: (1 + i*tg) * (s00 - s01*s10/(1+s11)); store by l-index
    #pragma unroll
    for (int j = 0; j < 8; ++j) {
        float denx = 1.0f + a6[j], deny = a7[j];
        float dinv = frcp(denx*denx + deny*deny);
        float numx = a2[j]*a4[j] - a3[j]*a5[j];
        float numy = a2[j]*a5[j] + a3[j]*a4[j];
        float qx = (numx*denx + numy*deny) * dinv;
        float qy = (numy*denx - numx*deny) * dinv;
        float kx = a0[j] - qx, ky = a1[j] - qy;
        float arx = kx - tg[j]*ky;
        float ary = ky + tg[j]*kx;
        if (lo) { Lx[ib + j] = arx; Ly[ib + j] = ary; }
        else    { Ux[ib + j] = arx; Uy[ib + j] = ary; }
    }
    if (tid == 0) {
        // l = 1024: tan -> inf limit, A[1024] = Re((step/2)*sum(conj(C)B))
        float sx = 0.f;
        for (int n = 0; n < NS; ++n) sx += cB[n].x;
        aMid = make_float2(0.5f * step * sx, 0.f);
    }
    __syncthreads();
    // ---- mirror-combine A and fill sA + DR-ordered sW (kspec input) ----
    for (int l = tid; l <= LSEQ/2; l += NTH) {
        float2 A;
        if (l == LSEQ/2) A = aMid;
        else A = make_float2(0.5f*(Lx[l] + Ux[l]), 0.5f*(Ly[l] - Uy[l]));
        sA[l + (l >> 7)] = A;
        sW[SW(DR11(l))] = A;
        if (l > 0 && l < LSEQ/2)
            sW[SW(DR11(LSEQ - l))] = make_float2(A.x, -A.y);
    }
    __syncthreads();
    // inverse DIT-2048 (DR -> natural time)
    pass8<true, true>(sW, tid << 3, 1, 0.f);
    __syncthreads();
    if (tid < 128) pass16<true>(sW, ((tid >> 3) << 7) | (tid & 7), 8,
                                TWO_PI * (float)(tid & 7) / 128.f);
    __syncthreads();
    if (tid < 128) pass16<true>(sW, tid, 128, TWO_PI * (float)tid / 2048.f);
    __syncthreads();
    // modulate: K[t]/2048 * e^{-2pi i t/4096}
    for (int t = tid; t < LSEQ; t += NTH) {
        float kv = sW[SW(t)].x * (1.0f / (float)LSEQ);
        float sn, cs;
        __sincosf(-TWO_PI * (float)t / (float)NF, &sn, &cs);
        sW[SW(t)] = make_float2(kv * cs, kv * sn);
    }
    __syncthreads();
    // forward DIF-2048 (natural -> DR spectrum)
    if (tid < 128) pass16<false>(sW, tid, 128, -TWO_PI * (float)tid / 2048.f);
    __syncthreads();
    if (tid < 128) pass16<false>(sW, ((tid >> 3) << 7) | (tid & 7), 8,
                                 -TWO_PI * (float)(tid & 7) / 128.f);
    __syncthreads();
    pass8<false, true>(sW, tid << 3, 1, 0.f);
    __syncthreads();
    const float dD = Dp[h];
    const float s4 = 1.0f / (float)NF;
    float2* Kh = KfP + (size_t)h * NF;
    #pragma unroll
    for (int g = 0; g < 8; ++g) {      // positions with (p>>8) odd <=> k odd
        int p = (2*g + 1) * 256 + tid;
        int k = ((p & 15) << 8) | (p & 240) | (p >> 8);
        int m = k >> 1;
        float2 v = sW[SW(DR11(m))];
        Kh[p] = make_float2((v.x + dD) * s4, v.y * s4);
    }
    #pragma unroll
    for (int g = 0; g < 8; ++g) {      // positions with (p>>8) even <=> k even
        int p = g * 512 + tid;         // k = ((tid&15)<<8)|(tid&240)|2g
        int m = (((tid & 15) << 7) | ((tid & 240) >> 1)) | g;   // = k>>1
        float2 v; float sgn;
        if (m <= 1024) { v = sA[m + (m >> 7)]; sgn = 1.f; }
        else { int mm = LSEQ - m; v = sA[mm + (mm >> 7)]; sgn = -1.f; }
        Kh[p] = make_float2((v.x + dD) * s4, sgn * v.y * s4);
    }
}

// FFT convolution: TWO sequences (same hp, b = 2*bb and 2*bb+1) per
// 512-thread block. Each 4-wave half owns one 4096-pt spectrum in its own
// 32-KB LDS region; barriers are shared. Kf row-pair (64 KB) is read once
// per block; the 4 same-hp blocks sit on one XCD (idx%8 = hp&7) so Kf is
// fetched ~once per XCD. Round-3 proven 60-us structure: every phase
// self-contained (no registers live across barriers).
__global__ __launch_bounds__(NTH2, 4) void k_conv(
    float2* __restrict__ W, const float2* __restrict__ Kf)
{
    __shared__ float2 s[2 * NF];
    const int idx = blockIdx.x;
    const int hp = ((idx >> 5) << 3) | (idx & 7);
    const int bb = (idx >> 3) & 3;
    const int half = threadIdx.x >> 8;
    const int t = threadIdx.x & 255;
    const int b = bb * 2 + half;
    float2* sh = s + (half << 12);
    float4* w4 = (float4*)(W + (((size_t)hp * NB + b) << 11));
    for (int i = t; i < 1024; i += 256) {
        float4 v = w4[i];
        sh[SW(2*i)]   = make_float2(v.x, v.y);
        sh[SW(2*i+1)] = make_float2(v.z, v.w);
    }
    __syncthreads();
    // forward DIF 4096 = 16*16*16 (pass 1 exploits zero top half)
    pass16_z(sh, t, 256, -TWO_PI * (float)t / 4096.f);
    __syncthreads();
    pass16<false>(sh, ((t >> 4) << 8) | (t & 15), 16,
                  -TWO_PI * (float)(t & 15) / 256.f);
    __syncthreads();
    pass16<false, true>(sh, t << 4, 1, 0.f);
    __syncthreads();
    // pointwise in permuted domain (pair-ownership: p <= pp, write both)
    const float2* K0 = Kf + (size_t)(2 * hp) * NF;
    const float2* K1 = K0 + NF;
    for (int p = t; p < NF; p += 256) {
        int k  = ((p & 15) << 8) | (p & 240) | (p >> 8);       // bin at pos p
        int kc = (NF - k) & (NF - 1);
        int pp = ((kc & 15) << 8) | (kc & 240) | (kc >> 8);    // conj bin pos
        if (p > pp) continue;
        if (p == pp) {   // self-conjugate bins (k = 0, 2048)
            float2 X = sh[SW(p)];
            float2 g0 = K0[p], g1 = K1[p];
            sh[SW(p)] = make_float2(X.x*g0.x - X.y*g1.y, X.x*g0.y + X.y*g1.x);
        } else {
            float2 Xa = sh[SW(p)], Xb = sh[SW(pp)];
            float2 U0 = make_float2(0.5f*(Xa.x + Xb.x), 0.5f*(Xa.y - Xb.y));
            float2 df = make_float2(Xa.x - Xb.x, Xa.y + Xb.y);
            float2 U1 = make_float2(0.5f*df.y, -0.5f*df.x);
            float2 A0 = K0[p], A1 = K1[p], B0 = K0[pp], B1 = K1[pp];
            float2 y0 = cmul(U0, A0), y1 = cmul(U1, A1);
            sh[SW(p)] = make_float2(y0.x - y1.y, y0.y + y1.x);
            float2 U0c = make_float2(U0.x, -U0.y);
            float2 U1c = make_float2(U1.x, -U1.y);
            float2 z0 = cmul(U0c, B0), z1 = cmul(U1c, B1);
            sh[SW(pp)] = make_float2(z0.x - z1.y, z0.y + z1.x);
        }
    }
    __syncthreads();
    // inverse DIT 4096 (last pass writes only t<2048)
    pass16<true, true>(sh, t << 4, 1, 0.f);
    __syncthreads();
    pass16<true>(sh, ((t >> 4) << 8) | (t & 15), 16,
                 TWO_PI * (float)(t & 15) / 256.f);
    __syncthreads();
    pass16_li(sh, t, 256, TWO_PI * (float)t / 4096.f);
    __syncthreads();
    for (int i = t; i < 1024; i += 256) {
        float2 a = sh[SW(2*i)], c = sh[SW(2*i+1)];
        w4[i] = make_float4(a.x, a.y, c.x, c.y);
    }
}

extern "C" void kernel_launch(void* const* d_in, const int* in_sizes, int n_in,
                              void* d_out, int out_size, void* d_ws, size_t ws_size,
                              hipStream_t stream) {
    const float* u   = (const float*)d_in[0];
    const float* Lre = (const float*)d_in[1];
    const float* Lim = (const float*)d_in[2];
    const float* P   = (const float*)d_in[3];
    const float* B   = (const float*)d_in[4];
    const float* C   = (const float*)d_in[5];
    const float* D   = (const float*)d_in[6];
    const float* ls  = (const float*)d_in[7];

    float2* KfP = (float2*)d_ws;                                   // 16.8 MB
    float2* W   = (float2*)((char*)d_ws +
                            (size_t)NH * NF * sizeof(float2));     // 33.6 MB

    k_tu    <<<dim3(32, 4, 8), NTH, 0, stream>>>((const float2*)u, W);
    k_ck    <<<NH, NTH, 0, stream>>>(Lre, Lim, P, B, C, ls, D, KfP);
    k_conv  <<<NPAIR * NB / 2, NTH2, 0, stream>>>(W, KfP);
    k_ty    <<<dim3(32, 4, 8), NTH, 0, stream>>>(W, (float2*)d_out);
}